// Round 9
// baseline (313.023 us; speedup 1.0000x reference)
//
#include <hip/hip_runtime.h>
#include <hip/hip_bf16.h>
#include <hip/hip_fp16.h>

#define HID 256
#define HEADS 4
#define DH 64
#define SLOPE 0.2f
#define NBMAX 512   // max buckets (Nn <= 65536)

typedef __attribute__((ext_vector_type(8))) _Float16 f16x8;
typedef __attribute__((ext_vector_type(4))) float f32x4;

__device__ inline float leaky(float x) { return x >= 0.f ? x : SLOPE * x; }
__device__ inline unsigned enc_f(float f) {
  unsigned u = __float_as_uint(f);
  return (u & 0x80000000u) ? ~u : (u | 0x80000000u);
}
__device__ inline float dec_f(unsigned u) {
  unsigned v = (u & 0x80000000u) ? (u & 0x7fffffffu) : ~u;
  return __uint_as_float(v);
}

// ---------- K0: Wt[n][k] = fp16(W[k][n]); block 0 zeros bucket_cnt ----------
__global__ __launch_bounds__(256) void transpose_w(const float* __restrict__ W,
                                                   _Float16* __restrict__ Wt,
                                                   int* __restrict__ bucket_cnt) {
  int n = blockIdx.x;
  int k = threadIdx.x;
  Wt[n * HID + k] = (_Float16)W[(size_t)k * HID + n];
  if (n == 0) {
    bucket_cnt[k] = 0;
    bucket_cnt[k + 256] = 0;
  }
}

// ---------- K1: Hp = fp16( X @ W ), head-major, fused a_s/a_d ----------
__global__ __launch_bounds__(512) void gemm_xw_f16(const float* __restrict__ X,
                                                   const _Float16* __restrict__ Wt,
                                                   const float* __restrict__ att_src,
                                                   const float* __restrict__ att_dst,
                                                   _Float16* __restrict__ Hp,
                                                   float* __restrict__ a_s,
                                                   float* __restrict__ a_d, int M) {
  __shared__ _Float16 sA[128][40];
  const int t = threadIdx.x;
  const int wave = t >> 6;
  const int l = t & 63;
  const int wm = wave >> 2;
  const int wn = wave & 3;
  const int row0 = blockIdx.x * 128;

  f32x4 acc[4][4] = {};

  for (int ks = 0; ks < 8; ++ks) {
    const int r = t >> 2;
    const int fo = (t & 3) * 8;
    const int gr = row0 + r;
    float4 v0 = make_float4(0.f, 0.f, 0.f, 0.f), v1 = v0;
    if (gr < M) {
      const float* p = X + (size_t)gr * HID + ks * 32 + fo;
      v0 = *(const float4*)p;
      v1 = *(const float4*)(p + 4);
    }
    _Float16 tmp[8] = {(_Float16)v0.x, (_Float16)v0.y, (_Float16)v0.z, (_Float16)v0.w,
                       (_Float16)v1.x, (_Float16)v1.y, (_Float16)v1.z, (_Float16)v1.w};
    __syncthreads();
    *(uint4*)&sA[r][fo] = *(uint4*)tmp;
    __syncthreads();

    f16x8 af[4];
#pragma unroll
    for (int mt = 0; mt < 4; ++mt)
      af[mt] = *(const f16x8*)&sA[wm * 64 + mt * 16 + (l & 15)][(l >> 4) * 8];
#pragma unroll
    for (int nt = 0; nt < 4; ++nt) {
      const f16x8 bfr = *(const f16x8*)(Wt + (size_t)(wn * 64 + nt * 16 + (l & 15)) * HID
                                        + ks * 32 + (l >> 4) * 8);
#pragma unroll
      for (int mt = 0; mt < 4; ++mt)
        acc[mt][nt] = __builtin_amdgcn_mfma_f32_16x16x32_f16(af[mt], bfr, acc[mt][nt], 0, 0, 0);
    }
  }

  const int head = wn;
  float as_v[4], ad_v[4];
#pragma unroll
  for (int nt = 0; nt < 4; ++nt) {
    as_v[nt] = att_src[head * DH + nt * 16 + (l & 15)];
    ad_v[nt] = att_dst[head * DH + nt * 16 + (l & 15)];
  }
#pragma unroll
  for (int mt = 0; mt < 4; ++mt) {
#pragma unroll
    for (int reg = 0; reg < 4; ++reg) {
      float ps = 0.f, pd = 0.f;
#pragma unroll
      for (int nt = 0; nt < 4; ++nt) {
        ps += acc[mt][nt][reg] * as_v[nt];
        pd += acc[mt][nt][reg] * ad_v[nt];
      }
#pragma unroll
      for (int off = 1; off < 16; off <<= 1) {
        ps += __shfl_xor(ps, off, 64);
        pd += __shfl_xor(pd, off, 64);
      }
      const int row = row0 + wm * 64 + mt * 16 + (l >> 4) * 4 + reg;
      if ((l & 15) == 0 && row < M) {
        a_s[(size_t)head * M + row] = ps;
        a_d[(size_t)head * M + row] = pd;
      }
    }
  }

#pragma unroll
  for (int mt = 0; mt < 4; ++mt) {
    const int rbase = row0 + wm * 64 + mt * 16 + (l >> 4) * 4;
#pragma unroll
    for (int nt = 0; nt < 4; ++nt) {
      const int dh = nt * 16 + (l & 15);
#pragma unroll
      for (int reg = 0; reg < 4; ++reg) {
        const int row = rbase + reg;
        if (row < M)
          Hp[((size_t)head * M + row) * DH + dh] = (_Float16)acc[mt][nt][reg];
      }
    }
  }
}

// ---------- A1: bucket histogram (bucket = dst>>7), LDS-aggregated ----------
__global__ __launch_bounds__(256) void bucket_hist(const int* __restrict__ ei, int E, int Etot,
                                                   int* __restrict__ bucket_cnt, int NB) {
  __shared__ int h[NBMAX];
  for (int i = threadIdx.x; i < NB; i += 256) h[i] = 0;
  __syncthreads();
  const int g0 = blockIdx.x * 1024;
#pragma unroll
  for (int j = 0; j < 4; ++j) {
    const int e0 = (g0 + j * 256 + threadIdx.x) * 4;
    if (e0 >= Etot) continue;
    if (e0 >= E) {
#pragma unroll
      for (int k = 0; k < 4; ++k) atomicAdd(&h[(e0 - E + k) >> 7], 1);
    } else {
      const int4 d4 = *(const int4*)(ei + E + e0);
      atomicAdd(&h[d4.x >> 7], 1);
      atomicAdd(&h[d4.y >> 7], 1);
      atomicAdd(&h[d4.z >> 7], 1);
      atomicAdd(&h[d4.w >> 7], 1);
    }
  }
  __syncthreads();
  for (int i = threadIdx.x; i < NB; i += 256)
    if (h[i]) atomicAdd(&bucket_cnt[i], h[i]);
}

// ---------- A2: scan bucket counts -> base & cursor ----------
__global__ __launch_bounds__(512) void scan_buckets(const int* __restrict__ bucket_cnt,
                                                    int* __restrict__ bucket_base,
                                                    int* __restrict__ bucket_cursor, int NB) {
  __shared__ int h[512];
  const int tid = threadIdx.x;
  const int v = (tid < NB) ? bucket_cnt[tid] : 0;
  h[tid] = v;
  __syncthreads();
#pragma unroll
  for (int off = 1; off < 512; off <<= 1) {
    const int t = (tid >= off) ? h[tid - off] : 0;
    __syncthreads();
    h[tid] += t;
    __syncthreads();
  }
  if (tid < NB) {
    const int base = h[tid] - v;
    bucket_base[tid] = base;
    bucket_cursor[tid] = base;
  }
}

// ---------- A3: scatter packed (dn_local<<16 | src) into block-reserved runs ----------
__global__ __launch_bounds__(256) void scatter_tmp(const int* __restrict__ ei, int E, int Etot,
                                                   int* __restrict__ bucket_cursor,
                                                   unsigned* __restrict__ tmp, int NB) {
  __shared__ int h[NBMAX];
  __shared__ int cur[NBMAX];
  for (int i = threadIdx.x; i < NB; i += 256) h[i] = 0;
  __syncthreads();
  const int g0 = blockIdx.x * 1024;
#pragma unroll
  for (int j = 0; j < 4; ++j) {
    const int e0 = (g0 + j * 256 + threadIdx.x) * 4;
    if (e0 >= Etot) continue;
    if (e0 >= E) {
#pragma unroll
      for (int k = 0; k < 4; ++k) atomicAdd(&h[(e0 - E + k) >> 7], 1);
    } else {
      const int4 d4 = *(const int4*)(ei + E + e0);
      atomicAdd(&h[d4.x >> 7], 1);
      atomicAdd(&h[d4.y >> 7], 1);
      atomicAdd(&h[d4.z >> 7], 1);
      atomicAdd(&h[d4.w >> 7], 1);
    }
  }
  __syncthreads();
  for (int i = threadIdx.x; i < NB; i += 256)
    cur[i] = h[i] ? atomicAdd(&bucket_cursor[i], h[i]) : 0;
  __syncthreads();
#pragma unroll
  for (int j = 0; j < 4; ++j) {
    const int e0 = (g0 + j * 256 + threadIdx.x) * 4;
    if (e0 >= Etot) continue;
    int s[4], dn[4];
    if (e0 >= E) {
#pragma unroll
      for (int k = 0; k < 4; ++k) { s[k] = e0 - E + k; dn[k] = s[k]; }
    } else {
      const int4 s4 = *(const int4*)(ei + e0);
      const int4 d4 = *(const int4*)(ei + E + e0);
      s[0] = s4.x; s[1] = s4.y; s[2] = s4.z; s[3] = s4.w;
      dn[0] = d4.x; dn[1] = d4.y; dn[2] = d4.z; dn[3] = d4.w;
    }
#pragma unroll
    for (int k = 0; k < 4; ++k) {
      const int b = dn[k] >> 7;
      const int pos = atomicAdd(&cur[b], 1);
      tmp[pos] = (unsigned)s[k] | ((unsigned)(dn[k] & 127) << 16);
    }
  }
}

// ---------- B: per-bucket counting sort -> packed csr (global writes, L2-local) ----------
__global__ __launch_bounds__(256) void csr_build(const unsigned* __restrict__ tmp,
                                                 const int* __restrict__ bucket_base,
                                                 const int* __restrict__ bucket_cursor,
                                                 unsigned* __restrict__ csr) {
  __shared__ int h[128], cur[128];
  const int b = blockIdx.x;
  const int start = bucket_base[b];
  const int cnt = bucket_cursor[b] - start;
  const int tid = threadIdx.x;
  if (tid < 128) h[tid] = 0;
  __syncthreads();
  for (int i = tid; i < cnt; i += 256)
    atomicAdd(&h[tmp[start + i] >> 16], 1);
  __syncthreads();
  const int own = (tid < 128) ? h[tid] : 0;
#pragma unroll
  for (int off = 1; off < 128; off <<= 1) {
    const int t = (tid < 128 && tid >= off) ? h[tid - off] : 0;
    __syncthreads();
    if (tid < 128) h[tid] += t;
    __syncthreads();
  }
  if (tid < 128) cur[tid] = h[tid] - own;
  __syncthreads();
  for (int i = tid; i < cnt; i += 256) {
    const unsigned p = tmp[start + i];
    const int pos = atomicAdd(&cur[p >> 16], 1);
    csr[start + pos] = p;
  }
}

// ---------- K6: per-(head,bucket) softmax + gather-aggregate ----------
// block = one head x one bucket (128 dst nodes, ~3200 contiguous packed edges).
// P1: edge-parallel max (LDS atomicMax); P3: exp-sum (LDS float atomicAdd);
// P5: 32 subgroups x 8 lanes stream contiguous edge runs, register-accumulate
//     (fp16 hfma2), segmented flush to LDS acc; P6: coalesced epilogue.
__global__ __launch_bounds__(256) void gat_bucket(const unsigned* __restrict__ csr,
                                                  const int* __restrict__ bucket_base,
                                                  const int* __restrict__ bucket_cursor,
                                                  const float* __restrict__ a_s,
                                                  const float* __restrict__ a_d,
                                                  const _Float16* __restrict__ Hp,
                                                  const float* __restrict__ bias,
                                                  float* __restrict__ out, int Nn, int NB) {
  __shared__ float accL[128][DH];
  __shared__ float adL[128];
  __shared__ unsigned mEnc[128];
  __shared__ float mL[128];
  __shared__ float lL[128];

  const int head = blockIdx.x / NB;
  const int b    = blockIdx.x - head * NB;
  const int tid  = threadIdx.x;
  const int start = bucket_base[b];
  const int cnt   = bucket_cursor[b] - start;
  const unsigned* __restrict__ ecsr = csr + start;
  const float* __restrict__ as_h = a_s + (size_t)head * Nn;
  const _Float16* __restrict__ Hph = Hp + (size_t)head * Nn * DH;

  // P0: init
  {
    float4 z = make_float4(0.f, 0.f, 0.f, 0.f);
    float* ap = &accL[tid >> 1][(tid & 1) * 32];
#pragma unroll
    for (int j = 0; j < 8; ++j) *(float4*)(ap + j * 4) = z;
    if (tid < 128) {
      const int n = b * 128 + tid;
      adL[tid] = (n < Nn) ? a_d[(size_t)head * Nn + n] : 0.f;
      mEnc[tid] = enc_f(-INFINITY);
      lL[tid] = 0.f;
    }
  }
  __syncthreads();

  // P1: per-node max
  for (int i = tid; i < cnt; i += 256) {
    const unsigned p = ecsr[i];
    const int dnl = p >> 16;
    const float logit = leaky(as_h[p & 0xffffu] + adL[dnl]);
    atomicMax(&mEnc[dnl], enc_f(logit));
  }
  __syncthreads();
  if (tid < 128) mL[tid] = dec_f(mEnc[tid]);
  __syncthreads();

  // P3: per-node sum of exp
  for (int i = tid; i < cnt; i += 256) {
    const unsigned p = ecsr[i];
    const int dnl = p >> 16;
    const float logit = leaky(as_h[p & 0xffffu] + adL[dnl]);
    atomicAdd(&lL[dnl], __expf(logit - mL[dnl]));
  }
  __syncthreads();
  if (tid < 128) lL[tid] = 1.f / (lL[tid] + 1e-16f);
  __syncthreads();

  // P5: gather-aggregate, contiguous run per subgroup
  {
    const int sg = tid >> 3;           // 0..31
    const int sl = tid & 7;            // dims sl*8 .. sl*8+7
    const int len = (cnt + 31) >> 5;
    const int i0 = sg * len;
    const int i1 = min(i0 + len, cnt);
    int prev = -1;
    __half2 racc[4];
#pragma unroll
    for (int j = 0; j < 4; ++j) racc[j] = __float2half2_rn(0.f);

    for (int i = i0; i < i1; ++i) {
      const unsigned p = ecsr[i];
      const int src = p & 0xffffu;
      const int dnl = p >> 16;
      if (dnl != prev) {
        if (prev >= 0) {
#pragma unroll
          for (int j = 0; j < 4; ++j) {
            const float2 f = __half22float2(racc[j]);
            atomicAdd(&accL[prev][sl * 8 + 2 * j], f.x);
            atomicAdd(&accL[prev][sl * 8 + 2 * j + 1], f.y);
            racc[j] = __float2half2_rn(0.f);
          }
        }
        prev = dnl;
      }
      const float logit = leaky(as_h[src] + adL[dnl]);
      const float alpha = __expf(logit - mL[dnl]) * lL[dnl];
      const __half2 a2 = __float2half2_rn(alpha);
      const uint4 hv = *(const uint4*)(Hph + (size_t)src * DH + sl * 8);
      racc[0] = __hfma2(a2, *(const __half2*)&hv.x, racc[0]);
      racc[1] = __hfma2(a2, *(const __half2*)&hv.y, racc[1]);
      racc[2] = __hfma2(a2, *(const __half2*)&hv.z, racc[2]);
      racc[3] = __hfma2(a2, *(const __half2*)&hv.w, racc[3]);
    }
    if (prev >= 0) {
#pragma unroll
      for (int j = 0; j < 4; ++j) {
        const float2 f = __half22float2(racc[j]);
        atomicAdd(&accL[prev][sl * 8 + 2 * j], f.x);
        atomicAdd(&accL[prev][sl * 8 + 2 * j + 1], f.y);
      }
    }
  }
  __syncthreads();

  // P6: epilogue
  {
    const int node = tid >> 1;
    const int d0 = (tid & 1) * 32;
    const int n = b * 128 + node;
    if (n < Nn) {
      float* op = out + (size_t)n * HID + head * DH + d0;
      const float* bp = bias + head * DH + d0;
#pragma unroll
      for (int k = 0; k < 8; ++k) {
        float4 v = *(const float4*)(&accL[node][d0 + k * 4]);
        const float4 bb = *(const float4*)(bp + k * 4);
        v.x = fmaxf(v.x + bb.x, 0.f);
        v.y = fmaxf(v.y + bb.y, 0.f);
        v.z = fmaxf(v.z + bb.z, 0.f);
        v.w = fmaxf(v.w + bb.w, 0.f);
        *(float4*)(op + k * 4) = v;
      }
    }
  }
}

extern "C" void kernel_launch(void* const* d_in, const int* in_sizes, int n_in,
                              void* d_out, int out_size, void* d_ws, size_t ws_size,
                              hipStream_t stream) {
  const float* x       = (const float*)d_in[0];
  const float* Wm      = (const float*)d_in[1];
  const float* att_src = (const float*)d_in[2];
  const float* att_dst = (const float*)d_in[3];
  const float* bias    = (const float*)d_in[4];
  const int*   ei      = (const int*)d_in[5];

  const int Nn   = in_sizes[0] / HID;   // 50000
  const int E    = in_sizes[5] / 2;     // 1200000
  const int Etot = E + Nn;              // 1250000
  const int NB   = (Nn + 127) >> 7;     // 391

  float* out = (float*)d_out;

  _Float16* Hp    = (_Float16*)d_ws;                     // [4][Nn][64] fp16
  _Float16* Wt    = Hp + (size_t)HEADS * Nn * DH;        // 256*256 fp16
  float* a_s      = (float*)(Wt + HID * HID);            // [4][Nn]
  float* a_d      = a_s + (size_t)HEADS * Nn;
  int*   bucket_cnt    = (int*)(a_d + (size_t)HEADS * Nn);
  int*   bucket_base   = bucket_cnt + NBMAX;
  int*   bucket_cursor = bucket_base + NBMAX;
  unsigned* tmp   = (unsigned*)(bucket_cursor + NBMAX);  // Etot u32
  unsigned* csr   = tmp + Etot;                          // Etot u32 (packed)

  const int nbEdge = (Etot + 4095) / 4096;  // 306

  transpose_w<<<HID, HID, 0, stream>>>(Wm, Wt, bucket_cnt);
  gemm_xw_f16<<<(Nn + 127) / 128, 512, 0, stream>>>(x, Wt, att_src, att_dst,
                                                    Hp, a_s, a_d, Nn);

  bucket_hist<<<nbEdge, 256, 0, stream>>>(ei, E, Etot, bucket_cnt, NB);
  scan_buckets<<<1, 512, 0, stream>>>(bucket_cnt, bucket_base, bucket_cursor, NB);
  scatter_tmp<<<nbEdge, 256, 0, stream>>>(ei, E, Etot, bucket_cursor, tmp, NB);
  csr_build<<<NB, 256, 0, stream>>>(tmp, bucket_base, bucket_cursor, csr);
  gat_bucket<<<HEADS * NB, 256, 0, stream>>>(csr, bucket_base, bucket_cursor,
                                             a_s, a_d, Hp, bias, out, Nn, NB);
}

// Round 10
// 176.056 us; speedup vs baseline: 1.7780x; 1.7780x over previous
//
#include <hip/hip_runtime.h>
#include <hip/hip_bf16.h>
#include <hip/hip_fp16.h>

#define HID 256
#define HEADS 4
#define DH 64
#define SLOPE 0.2f
#define NBMAX 512   // max buckets (Nn<=65536)
#define BCAP 4096   // max edges per bucket

typedef __attribute__((ext_vector_type(8))) _Float16 f16x8;
typedef __attribute__((ext_vector_type(4))) float f32x4;

__device__ inline float leaky(float x) { return x >= 0.f ? x : SLOPE * x; }

// ---------- K0: Wt[n][k] = fp16(W[k][n]); block 0 zeros bucket_cnt ----------
__global__ __launch_bounds__(256) void transpose_w(const float* __restrict__ W,
                                                   _Float16* __restrict__ Wt,
                                                   int* __restrict__ bucket_cnt) {
  int n = blockIdx.x;
  int k = threadIdx.x;
  Wt[n * HID + k] = (_Float16)W[(size_t)k * HID + n];
  if (n == 0) {
    bucket_cnt[k] = 0;
    bucket_cnt[k + 256] = 0;
  }
}

// ---------- K1: Hp = fp16( X @ W ), head-major, fused a_s/a_d ----------
__global__ __launch_bounds__(512) void gemm_xw_f16(const float* __restrict__ X,
                                                   const _Float16* __restrict__ Wt,
                                                   const float* __restrict__ att_src,
                                                   const float* __restrict__ att_dst,
                                                   _Float16* __restrict__ Hp,
                                                   float* __restrict__ a_s,
                                                   float* __restrict__ a_d, int M) {
  __shared__ _Float16 sA[128][40];
  const int t = threadIdx.x;
  const int wave = t >> 6;
  const int l = t & 63;
  const int wm = wave >> 2;
  const int wn = wave & 3;
  const int row0 = blockIdx.x * 128;

  f32x4 acc[4][4] = {};

  for (int ks = 0; ks < 8; ++ks) {
    const int r = t >> 2;
    const int fo = (t & 3) * 8;
    const int gr = row0 + r;
    float4 v0 = make_float4(0.f, 0.f, 0.f, 0.f), v1 = v0;
    if (gr < M) {
      const float* p = X + (size_t)gr * HID + ks * 32 + fo;
      v0 = *(const float4*)p;
      v1 = *(const float4*)(p + 4);
    }
    _Float16 tmp[8] = {(_Float16)v0.x, (_Float16)v0.y, (_Float16)v0.z, (_Float16)v0.w,
                       (_Float16)v1.x, (_Float16)v1.y, (_Float16)v1.z, (_Float16)v1.w};
    __syncthreads();
    *(uint4*)&sA[r][fo] = *(uint4*)tmp;
    __syncthreads();

    f16x8 af[4];
#pragma unroll
    for (int mt = 0; mt < 4; ++mt)
      af[mt] = *(const f16x8*)&sA[wm * 64 + mt * 16 + (l & 15)][(l >> 4) * 8];
#pragma unroll
    for (int nt = 0; nt < 4; ++nt) {
      const f16x8 bfr = *(const f16x8*)(Wt + (size_t)(wn * 64 + nt * 16 + (l & 15)) * HID
                                        + ks * 32 + (l >> 4) * 8);
#pragma unroll
      for (int mt = 0; mt < 4; ++mt)
        acc[mt][nt] = __builtin_amdgcn_mfma_f32_16x16x32_f16(af[mt], bfr, acc[mt][nt], 0, 0, 0);
    }
  }

  const int head = wn;
  float as_v[4], ad_v[4];
#pragma unroll
  for (int nt = 0; nt < 4; ++nt) {
    as_v[nt] = att_src[head * DH + nt * 16 + (l & 15)];
    ad_v[nt] = att_dst[head * DH + nt * 16 + (l & 15)];
  }
#pragma unroll
  for (int mt = 0; mt < 4; ++mt) {
#pragma unroll
    for (int reg = 0; reg < 4; ++reg) {
      float ps = 0.f, pd = 0.f;
#pragma unroll
      for (int nt = 0; nt < 4; ++nt) {
        ps += acc[mt][nt][reg] * as_v[nt];
        pd += acc[mt][nt][reg] * ad_v[nt];
      }
#pragma unroll
      for (int off = 1; off < 16; off <<= 1) {
        ps += __shfl_xor(ps, off, 64);
        pd += __shfl_xor(pd, off, 64);
      }
      const int row = row0 + wm * 64 + mt * 16 + (l >> 4) * 4 + reg;
      if ((l & 15) == 0 && row < M) {
        a_s[(size_t)head * M + row] = ps;
        a_d[(size_t)head * M + row] = pd;
      }
    }
  }

#pragma unroll
  for (int mt = 0; mt < 4; ++mt) {
    const int rbase = row0 + wm * 64 + mt * 16 + (l >> 4) * 4;
#pragma unroll
    for (int nt = 0; nt < 4; ++nt) {
      const int dh = nt * 16 + (l & 15);
#pragma unroll
      for (int reg = 0; reg < 4; ++reg) {
        const int row = rbase + reg;
        if (row < M)
          Hp[((size_t)head * M + row) * DH + dh] = (_Float16)acc[mt][nt][reg];
      }
    }
  }
}

// ---------- A1: bucket histogram (bucket = dst>>7), LDS-aggregated ----------
__global__ __launch_bounds__(256) void bucket_hist(const int* __restrict__ ei, int E, int Etot,
                                                   int* __restrict__ bucket_cnt, int NB) {
  __shared__ int h[NBMAX];
  for (int i = threadIdx.x; i < NB; i += 256) h[i] = 0;
  __syncthreads();
  const int g0 = blockIdx.x * 1024;
#pragma unroll
  for (int j = 0; j < 4; ++j) {
    const int e0 = (g0 + j * 256 + threadIdx.x) * 4;
    if (e0 >= Etot) continue;
    if (e0 >= E) {
#pragma unroll
      for (int k = 0; k < 4; ++k) atomicAdd(&h[(e0 - E + k) >> 7], 1);
    } else {
      const int4 d4 = *(const int4*)(ei + E + e0);
      atomicAdd(&h[d4.x >> 7], 1);
      atomicAdd(&h[d4.y >> 7], 1);
      atomicAdd(&h[d4.z >> 7], 1);
      atomicAdd(&h[d4.w >> 7], 1);
    }
  }
  __syncthreads();
  for (int i = threadIdx.x; i < NB; i += 256)
    if (h[i]) atomicAdd(&bucket_cnt[i], h[i]);
}

// ---------- A2: scan bucket counts -> base & cursor ----------
__global__ __launch_bounds__(512) void scan_buckets(const int* __restrict__ bucket_cnt,
                                                    int* __restrict__ bucket_base,
                                                    int* __restrict__ bucket_cursor,
                                                    int* __restrict__ offsets,
                                                    int Nn, int Etot, int NB) {
  __shared__ int h[512];
  const int tid = threadIdx.x;
  const int v = (tid < NB) ? bucket_cnt[tid] : 0;
  h[tid] = v;
  __syncthreads();
#pragma unroll
  for (int off = 1; off < 512; off <<= 1) {
    const int t = (tid >= off) ? h[tid - off] : 0;
    __syncthreads();
    h[tid] += t;
    __syncthreads();
  }
  if (tid < NB) {
    const int base = h[tid] - v;
    bucket_base[tid] = base;
    bucket_cursor[tid] = base;
  }
  if (tid == 0) offsets[Nn] = Etot;
}

// ---------- A3: scatter packed (dn_local<<16 | src) into block-reserved runs ----------
__global__ __launch_bounds__(256) void scatter_tmp(const int* __restrict__ ei, int E, int Etot,
                                                   int* __restrict__ bucket_cursor,
                                                   unsigned* __restrict__ tmp, int NB) {
  __shared__ int h[NBMAX];
  __shared__ int cur[NBMAX];
  for (int i = threadIdx.x; i < NB; i += 256) h[i] = 0;
  __syncthreads();
  const int g0 = blockIdx.x * 1024;
#pragma unroll
  for (int j = 0; j < 4; ++j) {
    const int e0 = (g0 + j * 256 + threadIdx.x) * 4;
    if (e0 >= Etot) continue;
    if (e0 >= E) {
#pragma unroll
      for (int k = 0; k < 4; ++k) atomicAdd(&h[(e0 - E + k) >> 7], 1);
    } else {
      const int4 d4 = *(const int4*)(ei + E + e0);
      atomicAdd(&h[d4.x >> 7], 1);
      atomicAdd(&h[d4.y >> 7], 1);
      atomicAdd(&h[d4.z >> 7], 1);
      atomicAdd(&h[d4.w >> 7], 1);
    }
  }
  __syncthreads();
  for (int i = threadIdx.x; i < NB; i += 256)
    cur[i] = h[i] ? atomicAdd(&bucket_cursor[i], h[i]) : 0;
  __syncthreads();
#pragma unroll
  for (int j = 0; j < 4; ++j) {
    const int e0 = (g0 + j * 256 + threadIdx.x) * 4;
    if (e0 >= Etot) continue;
    int s[4], dn[4];
    if (e0 >= E) {
#pragma unroll
      for (int k = 0; k < 4; ++k) { s[k] = e0 - E + k; dn[k] = s[k]; }
    } else {
      const int4 s4 = *(const int4*)(ei + e0);
      const int4 d4 = *(const int4*)(ei + E + e0);
      s[0] = s4.x; s[1] = s4.y; s[2] = s4.z; s[3] = s4.w;
      dn[0] = d4.x; dn[1] = d4.y; dn[2] = d4.z; dn[3] = d4.w;
    }
#pragma unroll
    for (int k = 0; k < 4; ++k) {
      const int b = dn[k] >> 7;
      const int pos = atomicAdd(&cur[b], 1);
      tmp[pos] = (unsigned)s[k] | ((unsigned)(dn[k] & 127) << 16);
    }
  }
}

// ---------- B: per-bucket counting sort in LDS -> offsets + csr_src ----------
__global__ __launch_bounds__(256) void csr_build(const unsigned* __restrict__ tmp,
                                                 const int* __restrict__ bucket_base,
                                                 const int* __restrict__ bucket_cursor,
                                                 int* __restrict__ offsets,
                                                 int* __restrict__ csr_src, int Nn) {
  __shared__ int h[128], cur[128];
  __shared__ int cs[BCAP];
  const int b = blockIdx.x;
  const int start = bucket_base[b];
  const int cnt = min(bucket_cursor[b] - start, BCAP);
  const int tid = threadIdx.x;
  if (tid < 128) h[tid] = 0;
  __syncthreads();
  for (int i = tid; i < cnt; i += 256)
    atomicAdd(&h[tmp[start + i] >> 16], 1);
  __syncthreads();
  const int own = (tid < 128) ? h[tid] : 0;
#pragma unroll
  for (int off = 1; off < 128; off <<= 1) {
    const int t = (tid < 128 && tid >= off) ? h[tid - off] : 0;
    __syncthreads();
    if (tid < 128) h[tid] += t;
    __syncthreads();
  }
  if (tid < 128) {
    const int excl = h[tid] - own;
    cur[tid] = excl;
    const int n = b * 128 + tid;
    if (n < Nn) offsets[n] = start + excl;
  }
  __syncthreads();
  for (int i = tid; i < cnt; i += 256) {
    const unsigned p = tmp[start + i];
    const int pos = atomicAdd(&cur[p >> 16], 1);
    cs[pos] = (int)(p & 0xffffu);
  }
  __syncthreads();
  for (int i = tid; i < cnt; i += 256)
    csr_src[start + i] = cs[i];
}

// ---------- K6: fused softmax + aggregate, head-split (head-major Hp) ----------
__global__ __launch_bounds__(256) void gat_agg2(const int* __restrict__ offsets,
                                                const int* __restrict__ csr_src,
                                                const float* __restrict__ a_s,
                                                const float* __restrict__ a_d,
                                                const _Float16* __restrict__ Hp,
                                                const float* __restrict__ bias,
                                                float* __restrict__ out, int Nn, int nbNode) {
  const int head = blockIdx.x / nbNode;
  const int nb   = blockIdx.x - head * nbNode;
  const int wave = threadIdx.x >> 6;
  const int lane = threadIdx.x & 63;
  const int half = lane >> 5;
  const int hl   = lane & 31;
  const int g2   = hl >> 3;
  const int sl   = hl & 7;
  const int n    = nb * 8 + wave * 2 + half;

  int start = 0, end = 0;
  if (n < Nn) { start = offsets[n]; end = offsets[n + 1]; }
  const float* __restrict__ as_h = a_s + (size_t)head * Nn;
  const float adn = (n < Nn) ? a_d[(size_t)head * Nn + n] : 0.f;
  const _Float16* __restrict__ Hh = Hp + (size_t)head * Nn * DH + sl * 8;

  float m = -INFINITY, l = 0.f;
  __half2 acc[4];
#pragma unroll
  for (int j = 0; j < 4; ++j) acc[j] = __float2half2_rn(0.f);

  const int nChunk = (end - start + 31) >> 5;
  for (int c = 0; c < nChunk; ++c) {
    const int base = start + c * 32;
    const int cnt = min(32, end - base);
    const int idx = min(base + hl, end - 1);
    const int src = csr_src[idx];
    const float lg = leaky(as_h[src] + adn);
    const float logit = (hl < cnt) ? lg : -INFINITY;

    float cm = logit;
#pragma unroll
    for (int off = 16; off > 0; off >>= 1) cm = fmaxf(cm, __shfl_xor(cm, off, 64));
    const float nm = fmaxf(m, cm);
    const float scale = __expf(m - nm);
    const __half2 s2 = __float2half2_rn(scale);
#pragma unroll
    for (int j = 0; j < 4; ++j) acc[j] = __hmul2(acc[j], s2);
    l *= scale;
    const float p = __expf(logit - nm);
    float psum = p;
#pragma unroll
    for (int off = 16; off > 0; off >>= 1) psum += __shfl_xor(psum, off, 64);
    l += psum;
    m = nm;

    const unsigned combo = (unsigned)src |
                           ((unsigned)__half_as_ushort(__float2half(p)) << 16);
    const int nIt = (cnt + 3) >> 2;
#pragma unroll 4
    for (int i = 0; i < nIt; ++i) {
      const int e = i * 4 + g2;
      const unsigned cc = (unsigned)__shfl((int)combo, half * 32 + e, 64);
      const unsigned se = cc & 0xffffu;
      const __half ah = __ushort_as_half((unsigned short)(cc >> 16));
      const __half2 a2 = __halves2half2(ah, ah);
      const uint4 hv = *(const uint4*)(Hh + (size_t)se * DH);
      acc[0] = __hfma2(a2, *(const __half2*)&hv.x, acc[0]);
      acc[1] = __hfma2(a2, *(const __half2*)&hv.y, acc[1]);
      acc[2] = __hfma2(a2, *(const __half2*)&hv.z, acc[2]);
      acc[3] = __hfma2(a2, *(const __half2*)&hv.w, acc[3]);
    }
  }
#pragma unroll
  for (int off = 8; off <= 16; off <<= 1)
#pragma unroll
    for (int j = 0; j < 4; ++j) {
      int tbits = __shfl_xor(*(const int*)&acc[j], off, 64);
      acc[j] = __hadd2(acc[j], *(const __half2*)&tbits);
    }

  if (hl < 8 && n < Nn) {
    const float inv = 1.f / (l + 1e-16f);
    float v[8];
#pragma unroll
    for (int j = 0; j < 4; ++j) {
      v[2 * j]     = __low2float(acc[j]);
      v[2 * j + 1] = __high2float(acc[j]);
    }
#pragma unroll
    for (int j = 0; j < 8; ++j)
      v[j] = fmaxf(v[j] * inv + bias[head * DH + sl * 8 + j], 0.f);
    float* op = out + (size_t)n * HID + head * DH + sl * 8;
    *(float4*)op = make_float4(v[0], v[1], v[2], v[3]);
    *(float4*)(op + 4) = make_float4(v[4], v[5], v[6], v[7]);
  }
}

extern "C" void kernel_launch(void* const* d_in, const int* in_sizes, int n_in,
                              void* d_out, int out_size, void* d_ws, size_t ws_size,
                              hipStream_t stream) {
  const float* x       = (const float*)d_in[0];
  const float* Wm      = (const float*)d_in[1];
  const float* att_src = (const float*)d_in[2];
  const float* att_dst = (const float*)d_in[3];
  const float* bias    = (const float*)d_in[4];
  const int*   ei      = (const int*)d_in[5];

  const int Nn   = in_sizes[0] / HID;   // 50000
  const int E    = in_sizes[5] / 2;     // 1200000
  const int Etot = E + Nn;              // 1250000
  const int NB   = (Nn + 127) >> 7;     // 391

  float* out = (float*)d_out;

  _Float16* Hp    = (_Float16*)d_ws;                     // [4][Nn][64] fp16
  _Float16* Wt    = Hp + (size_t)HEADS * Nn * DH;        // 256*256 fp16
  float* a_s      = (float*)(Wt + HID * HID);            // [4][Nn]
  float* a_d      = a_s + (size_t)HEADS * Nn;
  int*   offsets  = (int*)(a_d + (size_t)HEADS * Nn);    // Nn+1
  int*   bucket_cnt    = offsets + (Nn + 1);
  int*   bucket_base   = bucket_cnt + NBMAX;
  int*   bucket_cursor = bucket_base + NBMAX;
  unsigned* tmp   = (unsigned*)(bucket_cursor + NBMAX);  // Etot u32
  int*   csr_src  = (int*)(tmp + Etot);                  // Etot

  const int nbNode = (Nn + 7) / 8;       // 6250
  const int nbEdge = (Etot + 4095) / 4096;  // 306

  transpose_w<<<HID, HID, 0, stream>>>(Wm, Wt, bucket_cnt);
  gemm_xw_f16<<<(Nn + 127) / 128, 512, 0, stream>>>(x, Wt, att_src, att_dst,
                                                    Hp, a_s, a_d, Nn);

  bucket_hist<<<nbEdge, 256, 0, stream>>>(ei, E, Etot, bucket_cnt, NB);
  scan_buckets<<<1, 512, 0, stream>>>(bucket_cnt, bucket_base, bucket_cursor,
                                      offsets, Nn, Etot, NB);
  scatter_tmp<<<nbEdge, 256, 0, stream>>>(ei, E, Etot, bucket_cursor, tmp, NB);
  csr_build<<<NB, 256, 0, stream>>>(tmp, bucket_base, bucket_cursor,
                                    offsets, csr_src, Nn);
  gat_agg2<<<HEADS * nbNode, 256, 0, stream>>>(offsets, csr_src, a_s, a_d, Hp, bias,
                                               out, Nn, nbNode);
}